// Round 2
// baseline (731.121 us; speedup 1.0000x reference)
//
#include <hip/hip_runtime.h>
#include <cstdint>
#include <cstddef>

#define TSEQ 2048
#define DDIM 1024

typedef _Float16 f16;
typedef _Float16 f16x4 __attribute__((ext_vector_type(4)));
typedef _Float16 f16x8 __attribute__((ext_vector_type(8)));
typedef float f32x4 __attribute__((ext_vector_type(4)));
typedef float f32x16 __attribute__((ext_vector_type(16)));

// 16B of zeros for out-of-range (causal pad) staging loads
__device__ __align__(16) static const unsigned char g_zero16[16] = {};

__device__ __forceinline__ void gload_lds16(const void* g, void* l) {
  __builtin_amdgcn_global_load_lds(
      (const __attribute__((address_space(1))) void*)g,
      (__attribute__((address_space(3))) void*)l, 16, 0, 0);
}

// ---------------- fp32 -> fp16 convert (vectorized) ----------------
__global__ void cvt_f32_f16(const float* __restrict__ src, f16* __restrict__ dst, int n4) {
  int i = blockIdx.x * 256 + threadIdx.x;
  if (i >= n4) return;
  float4 v = ((const float4*)src)[i];
  f16x4 h = { (f16)v.x, (f16)v.y, (f16)v.z, (f16)v.w };
  ((f16x4*)dst)[i] = h;
}

// ------- weight convert+transpose: w[o][i][W] -> wh[o][w*D + i] -------
__global__ void cvt_w_transpose(const float* __restrict__ qw, const float* __restrict__ kw,
                                f16* __restrict__ qwh, f16* __restrict__ kwh) {
  __shared__ float tile[64 * 17];
  int o = blockIdx.x;
  const float* src;
  f16* dst;
  if (o < 1024) { src = qw + (size_t)o * 16384; dst = qwh + (size_t)o * 16384; }
  else          { src = kw + (size_t)(o - 1024) * 16384; dst = kwh + (size_t)(o - 1024) * 16384; }
  for (int i0 = 0; i0 < 1024; i0 += 64) {
    __syncthreads();
    #pragma unroll
    for (int p = 0; p < 4; p++) {
      int idx = p * 256 + threadIdx.x;           // flat = ii*16 + w
      float v = src[i0 * 16 + idx];
      tile[(idx >> 4) * 17 + (idx & 15)] = v;    // [ii][w] padded
    }
    __syncthreads();
    #pragma unroll
    for (int p = 0; p < 4; p++) {
      int idx = p * 256 + threadIdx.x;           // w = idx/64, ii = idx%64
      int w = idx >> 6, ii = idx & 63;
      dst[w * 1024 + i0 + ii] = (f16)tile[ii * 17 + w];
    }
  }
}

// ---------------- MFMA GEMM: conv-as-GEMM / plain GEMM ----------------
// 2 waves/block, block tile 128x128, wave tile 128x64 (4x2 frags of 32x32x16).
// LDS stored as 16B chunks, slot swizzle c' = c ^ (r&3) -> conflict-free reads.
// MODE 0: A=xh, blockIdx.y selects q (KW=16) / k (KW=16) / v (KW=1), fp16 out
// MODE 1: A=outh, p-projection, fp32 out to d_out
template<int MODE>
__global__ __launch_bounds__(128, 2) void gemm_k(
    const f16* __restrict__ Abase,
    const f16* __restrict__ Bq, const f16* __restrict__ Bk, const f16* __restrict__ Bv,
    const float* __restrict__ bq, const float* __restrict__ bk, const float* __restrict__ bv,
    f16* __restrict__ oq, f16* __restrict__ okk, f16* __restrict__ ov,
    float* __restrict__ of)
{
  __shared__ f16 As[128 * 32];   // 128 rows x 4 chunks x 8 f16 (swizzled slots)
  __shared__ f16 Bs[128 * 32];
  const int tid = threadIdx.x;
  const int lane = tid & 63;
  const int wid = tid >> 6;        // 0..1 = wave's n-half
  const int mtile = blockIdx.x;
  const int yt = blockIdx.y;

  const f16* Bp; const float* bias; f16* oh = nullptr; float* ofp = nullptr;
  int K, KW, n0;
  if (MODE == 0) {
    if (yt < 8)       { Bp = Bq; bias = bq; oh = oq;  K = 16384; KW = 16; n0 = yt * 128; }
    else if (yt < 16) { Bp = Bk; bias = bk; oh = okk; K = 16384; KW = 16; n0 = (yt - 8) * 128; }
    else              { Bp = Bv; bias = bv; oh = ov;  K = 1024;  KW = 1;  n0 = (yt - 16) * 128; }
  } else {
    Bp = Bq; bias = bq; ofp = of; K = 1024; KW = 1; n0 = yt * 128;
  }

  const int m0 = mtile * 128;
  const int bT = m0 & ~(TSEQ - 1);     // batch base row
  const int t0 = m0 & (TSEQ - 1);      // within-batch t

  f32x16 acc[4][2] = {};

  for (int kk = 0; kk < K; kk += 32) {
    __syncthreads();
    {
      const int w = kk >> 10;                    // conv tap (0 for K=1024)
      const int i0k = kk & (DDIM - 1);           // channel offset (halves)
      #pragma unroll
      for (int c = 0; c < 4; c++) {
        const int s_id = (wid * 4 + c) * 64 + lane;   // A chunk slot 0..511
        const int r = s_id >> 2;                       // tile row 0..127
        const int cg = (s_id & 3) ^ (r & 3);           // swizzled global chunk
        const int srcT = t0 + r + w - (KW - 1);
        const void* g = (srcT >= 0)
            ? (const void*)(Abase + (((size_t)(bT + srcT)) << 10) + i0k + cg * 8)
            : (const void*)g_zero16;
        gload_lds16(g, (void*)&As[(wid * 4 + c) * 512]);
      }
      #pragma unroll
      for (int c = 0; c < 4; c++) {
        const int s_id = (wid * 4 + c) * 64 + lane;   // B chunk slot 0..511
        const int r = s_id >> 2;                       // B row (output col) 0..127
        const int cg = (s_id & 3) ^ (r & 3);
        const void* g = (const void*)(Bp + (size_t)(n0 + r) * K + kk + cg * 8);
        gload_lds16(g, (void*)&Bs[(wid * 4 + c) * 512]);
      }
    }
    __syncthreads();
    #pragma unroll
    for (int s = 0; s < 2; s++) {
      f16x8 af[4], bf[2];
      const int cbase = s * 2 + (lane >> 5);
      const int csw = lane & 3;
      #pragma unroll
      for (int i = 0; i < 4; i++) {
        const int r = i * 32 + (lane & 31);
        af[i] = *(const f16x8*)&As[r * 32 + ((cbase ^ csw) * 8)];
      }
      #pragma unroll
      for (int j = 0; j < 2; j++) {
        const int r = wid * 64 + j * 32 + (lane & 31);
        bf[j] = *(const f16x8*)&Bs[r * 32 + ((cbase ^ csw) * 8)];
      }
      #pragma unroll
      for (int i = 0; i < 4; i++)
        #pragma unroll
        for (int j = 0; j < 2; j++)
          acc[i][j] = __builtin_amdgcn_mfma_f32_32x32x16_f16(af[i], bf[j], acc[i][j], 0, 0, 0);
    }
  }

  // epilogue: 32x32 C/D layout col=lane&31, row=(reg&3)+8*(reg>>2)+4*(lane>>5)
  const int ccol = lane & 31;
  const int rbase = 4 * (lane >> 5);
  #pragma unroll
  for (int j = 0; j < 2; j++) {
    const int col = n0 + wid * 64 + j * 32 + ccol;
    const float bvl = bias[col];
    #pragma unroll
    for (int i = 0; i < 4; i++) {
      #pragma unroll
      for (int reg = 0; reg < 16; reg++) {
        const int row = m0 + i * 32 + (reg & 3) + 8 * (reg >> 2) + rbase;
        const float val = acc[i][j][reg] + bvl;
        if (MODE == 1) ofp[(size_t)row * DDIM + col] = val;
        else           oh[(size_t)row * DDIM + col] = (f16)val;
      }
    }
  }
}

// ------- log-sparse scores: s[bh,e,t] = q[t]·k[(t+2^e)%T] * scale -------
__global__ void score_k(const f16* __restrict__ qh, const f16* __restrict__ kh,
                        float* __restrict__ scores) {
  int bid = blockIdx.x;            // 256 blocks
  int bh = bid >> 3, tc = bid & 7;
  int b = bh >> 4, h = bh & 15;
  int t = tc * 256 + threadIdx.x;
  const f16* qrow = qh + (((size_t)(b * TSEQ + t)) << 10) + h * 64;
  float qv[64];
  #pragma unroll
  for (int c = 0; c < 8; c++) {
    f16x8 v = *(const f16x8*)(qrow + c * 8);
    #pragma unroll
    for (int j = 0; j < 8; j++) qv[c * 8 + j] = (float)v[j];
  }
  #pragma unroll
  for (int e = 0; e < 8; e++) {
    int ts = t + (1 << e);
    if (ts >= TSEQ) ts -= TSEQ;      // jnp.roll wraps
    const f16* krow = kh + (((size_t)(b * TSEQ + ts)) << 10) + h * 64;
    float s = 0.f;
    #pragma unroll
    for (int c = 0; c < 8; c++) {
      f16x8 v = *(const f16x8*)(krow + c * 8);
      #pragma unroll
      for (int j = 0; j < 8; j++) s += qv[c * 8 + j] * (float)v[j];
    }
    scores[((size_t)(bh * 8 + e) << 11) + t] = s * 0.125f;
  }
}

// ---- in-place softmax over T per (b,h,e) row: 256 rows of 2048 ----
__global__ void softmax_k(float* __restrict__ scores) {
  __shared__ float red[4];
  int row = blockIdx.x;
  float* p = scores + ((size_t)row << 11);
  int tid = threadIdx.x;
  float v[8];
  float4 a = ((const float4*)p)[tid * 2];
  float4 b = ((const float4*)p)[tid * 2 + 1];
  v[0] = a.x; v[1] = a.y; v[2] = a.z; v[3] = a.w;
  v[4] = b.x; v[5] = b.y; v[6] = b.z; v[7] = b.w;
  float m = v[0];
  #pragma unroll
  for (int j = 1; j < 8; j++) m = fmaxf(m, v[j]);
  for (int o = 32; o > 0; o >>= 1) m = fmaxf(m, __shfl_xor(m, o, 64));
  if ((tid & 63) == 0) red[tid >> 6] = m;
  __syncthreads();
  m = fmaxf(fmaxf(red[0], red[1]), fmaxf(red[2], red[3]));
  __syncthreads();
  float s = 0.f;
  #pragma unroll
  for (int j = 0; j < 8; j++) { v[j] = __expf(v[j] - m); s += v[j]; }
  for (int o = 32; o > 0; o >>= 1) s += __shfl_xor(s, o, 64);
  if ((tid & 63) == 0) red[tid >> 6] = s;
  __syncthreads();
  s = (red[0] + red[1]) + (red[2] + red[3]);
  float inv = 1.0f / s;
  float4 o1 = make_float4(v[0] * inv, v[1] * inv, v[2] * inv, v[3] * inv);
  float4 o2 = make_float4(v[4] * inv, v[5] * inv, v[6] * inv, v[7] * inv);
  ((float4*)p)[tid * 2] = o1;
  ((float4*)p)[tid * 2 + 1] = o2;
}

// ------- local windowed attention + log-sparse combine -> outh -------
__global__ __launch_bounds__(256) void attn_out_k(
    const f16* __restrict__ qh, const f16* __restrict__ kh, const f16* __restrict__ vh,
    const float* __restrict__ alpha, f16* __restrict__ outh)
{
  __shared__ f16 qL[128 * 64];     // 16 KB
  __shared__ f16 vL[271 * 64];     // 33.9 KB: rows t0-15 .. t0+255 (wrap)
  __shared__ float scL[128 * 16];  // 8 KB
  __shared__ float aL[8 * 128];    // 4 KB
  const int bh = blockIdx.x, tc = blockIdx.y;
  const int b = bh >> 4, h = bh & 15;
  const int t0 = tc * 128;
  const int tid = threadIdx.x;
  const size_t base = (((size_t)(b * TSEQ)) << 10) + h * 64;

  // phase 1: cooperative loads
  for (int idx = tid; idx < 128 * 8; idx += 256) {
    int r = idx >> 3, c = idx & 7;
    *(uint4*)&qL[r * 64 + c * 8] = *(const uint4*)(qh + base + (((size_t)(t0 + r)) << 10) + c * 8);
  }
  for (int idx = tid; idx < 271 * 8; idx += 256) {
    int j = idx >> 3, c = idx & 7;
    int r = t0 - 15 + j;
    uint4 val;
    if (r < 0) val = make_uint4(0, 0, 0, 0);
    else {
      int rr = (r >= TSEQ) ? r - TSEQ : r;     // wrap for log-sparse rows
      val = *(const uint4*)(vh + base + (((size_t)rr) << 10) + c * 8);
    }
    *(uint4*)&vL[j * 64 + c * 8] = val;
  }
  {
    int e = tid >> 5, t4 = (tid & 31) * 4;
    *(float4*)&aL[e * 128 + t4] =
        *(const float4*)(alpha + ((size_t)(bh * 8 + e) << 11) + t0 + t4);
  }
  __syncthreads();

  // phase 2: local scores (zero-pad rows give score exactly 0, kept in softmax)
  {
    const int tl = tid & 127;
    const int wg = tid >> 7;
    float qv[64];
    #pragma unroll
    for (int c = 0; c < 8; c++) {
      f16x8 v = *(const f16x8*)&qL[tl * 64 + c * 8];
      #pragma unroll
      for (int j = 0; j < 8; j++) qv[c * 8 + j] = (float)v[j];
    }
    #pragma unroll
    for (int wi = 0; wi < 8; wi++) {
      const int w = wg * 8 + wi;
      const int r = t0 + tl - 15 + w;
      float s = 0.f;
      if (r >= 0) {
        const f16* kr = kh + base + (((size_t)r) << 10);
        #pragma unroll
        for (int c = 0; c < 8; c++) {
          f16x8 v = *(const f16x8*)(kr + c * 8);
          #pragma unroll
          for (int j = 0; j < 8; j++) s += qv[c * 8 + j] * (float)v[j];
        }
      }
      scL[tl * 16 + w] = s * 0.125f;
    }
  }
  __syncthreads();

  // phase 3: 16-wide softmax per t
  if (tid < 128) {
    float sc[16];
    float m = -1e30f;
    #pragma unroll
    for (int w = 0; w < 16; w++) { sc[w] = scL[tid * 16 + w]; m = fmaxf(m, sc[w]); }
    float sum = 0.f;
    #pragma unroll
    for (int w = 0; w < 16; w++) { sc[w] = __expf(sc[w] - m); sum += sc[w]; }
    float inv = 1.0f / sum;
    #pragma unroll
    for (int w = 0; w < 16; w++) scL[tid * 16 + w] = sc[w] * inv;
  }
  __syncthreads();

  // phase 4: out = local + log-sparse
  {
    const int tl = tid >> 1;
    const int d0 = (tid & 1) * 32;
    float accv[32] = {};
    #pragma unroll
    for (int w = 0; w < 16; w++) {
      const float pw_ = scL[tl * 16 + w];
      const f16* vr = &vL[(tl + w) * 64 + d0];
      #pragma unroll
      for (int c = 0; c < 4; c++) {
        f16x8 v = *(const f16x8*)(vr + c * 8);
        #pragma unroll
        for (int j = 0; j < 8; j++) accv[c * 8 + j] += pw_ * (float)v[j];
      }
    }
    #pragma unroll
    for (int e = 0; e < 8; e++) {
      const float a = aL[e * 128 + tl];
      const f16* vr = &vL[(tl + 15 + (1 << e)) * 64 + d0];
      #pragma unroll
      for (int c = 0; c < 4; c++) {
        f16x8 v = *(const f16x8*)(vr + c * 8);
        #pragma unroll
        for (int j = 0; j < 8; j++) accv[c * 8 + j] += a * (float)v[j];
      }
    }
    f16* orow = outh + base + (((size_t)(t0 + tl)) << 10) + d0;
    #pragma unroll
    for (int c = 0; c < 4; c++) {
      f16x8 v;
      #pragma unroll
      for (int j = 0; j < 8; j++) v[j] = (f16)accv[c * 8 + j];
      *(f16x8*)(orow + c * 8) = v;
    }
  }
}

extern "C" void kernel_launch(void* const* d_in, const int* in_sizes, int n_in,
                              void* d_out, int out_size, void* d_ws, size_t ws_size,
                              hipStream_t stream) {
  (void)in_sizes; (void)n_in; (void)out_size; (void)ws_size;
  const float* x   = (const float*)d_in[0];
  const float* q_w = (const float*)d_in[1];
  const float* q_b = (const float*)d_in[2];
  const float* k_w = (const float*)d_in[3];
  const float* k_b = (const float*)d_in[4];
  const float* v_w = (const float*)d_in[5];
  const float* v_b = (const float*)d_in[6];
  const float* p_w = (const float*)d_in[7];
  const float* p_b = (const float*)d_in[8];
  float* out = (float*)d_out;

  char* ws = (char*)d_ws;
  f16* xh      = (f16*)(ws);                 //  8.4 MB
  f16* qwh     = (f16*)(ws + 8388608);       // 33.6 MB  [o][w*D+i]
  f16* kwh     = (f16*)(ws + 41943040);      // 33.6 MB
  f16* vwh     = (f16*)(ws + 75497472);      //  2.1 MB
  f16* pwh     = (f16*)(ws + 77594624);      //  2.1 MB
  f16* qh      = (f16*)(ws + 79691776);      //  8.4 MB  (B,T,D)
  f16* kh      = (f16*)(ws + 88080384);      //  8.4 MB
  f16* vh      = (f16*)(ws + 96468992);      //  8.4 MB
  f16* outh    = (f16*)(ws + 104857600);     //  8.4 MB
  float* alpha = (float*)(ws + 113246208);   //  2.1 MB  (B*H*E, T) scores->alpha
  // total 115.4 MB

  cvt_f32_f16<<<4096, 256, 0, stream>>>(x, xh, 1048576);
  cvt_f32_f16<<<1024, 256, 0, stream>>>(v_w, vwh, 262144);
  cvt_f32_f16<<<1024, 256, 0, stream>>>(p_w, pwh, 262144);
  cvt_w_transpose<<<2048, 256, 0, stream>>>(q_w, k_w, qwh, kwh);

  // fused q/k/v GEMM: yt 0-7 q (K=16384), 8-15 k, 16-23 v (K=1024)
  gemm_k<0><<<dim3(32, 24), 128, 0, stream>>>(xh, qwh, kwh, vwh, q_b, k_b, v_b,
                                              qh, kh, vh, nullptr);

  score_k<<<256, 256, 0, stream>>>(qh, kh, alpha);
  softmax_k<<<256, 256, 0, stream>>>(alpha);
  attn_out_k<<<dim3(32, 16), 256, 0, stream>>>(qh, kh, vh, alpha, outh);

  // final projection -> fp32 d_out
  gemm_k<1><<<dim3(32, 8), 128, 0, stream>>>(outh, pwh, nullptr, nullptr, p_b,
                                             nullptr, nullptr, nullptr, nullptr,
                                             nullptr, out);
}

// Round 3
// 600.038 us; speedup vs baseline: 1.2185x; 1.2185x over previous
//
#include <hip/hip_runtime.h>
#include <cstdint>
#include <cstddef>

#define TSEQ 2048
#define DDIM 1024

typedef _Float16 f16;
typedef _Float16 f16x4 __attribute__((ext_vector_type(4)));
typedef _Float16 f16x8 __attribute__((ext_vector_type(8)));
typedef float f32x4 __attribute__((ext_vector_type(4)));

// 16B of zeros for out-of-range (causal pad) staging loads
__device__ __align__(16) static const unsigned char g_zero16[16] = {};

__device__ __forceinline__ void gload_lds16(const void* g, void* l) {
  __builtin_amdgcn_global_load_lds(
      (const __attribute__((address_space(1))) void*)g,
      (__attribute__((address_space(3))) void*)l, 16, 0, 0);
}

// ---------------- fp32 -> fp16 convert (vectorized) ----------------
__global__ void cvt_f32_f16(const float* __restrict__ src, f16* __restrict__ dst, int n4) {
  int i = blockIdx.x * 256 + threadIdx.x;
  if (i >= n4) return;
  float4 v = ((const float4*)src)[i];
  f16x4 h = { (f16)v.x, (f16)v.y, (f16)v.z, (f16)v.w };
  ((f16x4*)dst)[i] = h;
}

// ------- weight convert+transpose: w[o][i][W] -> wh[o][w*D + i] -------
__global__ void cvt_w_transpose(const float* __restrict__ qw, const float* __restrict__ kw,
                                f16* __restrict__ qwh, f16* __restrict__ kwh) {
  __shared__ float tile[64 * 17];
  int o = blockIdx.x;
  const float* src;
  f16* dst;
  if (o < 1024) { src = qw + (size_t)o * 16384; dst = qwh + (size_t)o * 16384; }
  else          { src = kw + (size_t)(o - 1024) * 16384; dst = kwh + (size_t)(o - 1024) * 16384; }
  for (int i0 = 0; i0 < 1024; i0 += 64) {
    __syncthreads();
    #pragma unroll
    for (int p = 0; p < 4; p++) {
      int idx = p * 256 + threadIdx.x;           // flat = ii*16 + w
      float v = src[i0 * 16 + idx];
      tile[(idx >> 4) * 17 + (idx & 15)] = v;    // [ii][w] padded
    }
    __syncthreads();
    #pragma unroll
    for (int p = 0; p < 4; p++) {
      int idx = p * 256 + threadIdx.x;           // w = idx/64, ii = idx%64
      int w = idx >> 6, ii = idx & 63;
      dst[w * 1024 + i0 + ii] = (f16)tile[ii * 17 + w];
    }
  }
}

// ---------------- MFMA GEMM: conv-as-GEMM / plain GEMM ----------------
// Round-1 structure (4 waves, 128x128 block tile, 16x16x32 MFMA) plus the
// CORRECT bank swizzle: row r, global 16B chunk c lives at slot c ^ ((r>>1)&3).
// Bank group of a slot = (r&1)*4 | slot -> 16 consecutive rows sweep all 8
// groups exactly 2x (2-way is free). XOR cancels on read: numerics identical.
// MODE 0: A=xh, blockIdx.y selects q (KW=16) / k (KW=16) / v (KW=1), fp16 out
// MODE 1: A=outh, p-projection, fp32 out to d_out
template<int MODE>
__global__ __launch_bounds__(256, 2) void gemm_k(
    const f16* __restrict__ Abase,
    const f16* __restrict__ Bq, const f16* __restrict__ Bk, const f16* __restrict__ Bv,
    const float* __restrict__ bq, const float* __restrict__ bk, const float* __restrict__ bv,
    f16* __restrict__ oq, f16* __restrict__ okk, f16* __restrict__ ov,
    float* __restrict__ of)
{
  __shared__ f16 As[128 * 32];
  __shared__ f16 Bs[128 * 32];
  const int tid = threadIdx.x;
  const int lane = tid & 63;
  const int wid = tid >> 6;
  const int mtile = blockIdx.x;
  const int yt = blockIdx.y;

  const f16* Bp; const float* bias; f16* oh = nullptr; float* ofp = nullptr;
  int K, KW, n0;
  if (MODE == 0) {
    if (yt < 8)       { Bp = Bq; bias = bq; oh = oq;  K = 16384; KW = 16; n0 = yt * 128; }
    else if (yt < 16) { Bp = Bk; bias = bk; oh = okk; K = 16384; KW = 16; n0 = (yt - 8) * 128; }
    else              { Bp = Bv; bias = bv; oh = ov;  K = 1024;  KW = 1;  n0 = (yt - 16) * 128; }
  } else {
    Bp = Bq; bias = bq; ofp = of; K = 1024; KW = 1; n0 = yt * 128;
  }

  const int m0 = mtile * 128;
  const int bT = m0 & ~(TSEQ - 1);     // batch base row
  const int t0 = m0 & (TSEQ - 1);      // within-batch t

  const int srow = lane >> 2;                          // staging row within 16-row chunk
  const int scg = ((lane & 3) ^ ((lane >> 3) & 3)) * 8; // swizzled global chunk (halves)
  const int wm = wid & 1;
  const int wn = wid >> 1;

  f32x4 acc[4][4] = {};

  for (int kk = 0; kk < K; kk += 32) {
    __syncthreads();
    if (wid < 2) {
      const int w = kk >> 10;                    // conv tap (0 for K=1024)
      const int i0k = (kk & (DDIM - 1)) + scg;   // channel offset (halves)
      #pragma unroll
      for (int c = 0; c < 4; c++) {
        const int r = wid * 64 + c * 16 + srow;
        const int srcT = t0 + r + w - (KW - 1);
        const void* g = (srcT >= 0)
            ? (const void*)(Abase + (((size_t)(bT + srcT)) << 10) + i0k)
            : (const void*)g_zero16;
        gload_lds16(g, (void*)&As[(wid * 64 + c * 16) * 32]);
      }
    } else {
      #pragma unroll
      for (int c = 0; c < 4; c++) {
        const int r = (wid - 2) * 64 + c * 16 + srow;
        const void* g = (const void*)(Bp + (size_t)(n0 + r) * K + kk + scg);
        gload_lds16(g, (void*)&Bs[((wid - 2) * 64 + c * 16) * 32]);
      }
    }
    __syncthreads();
    // read slot = (lane>>4) ^ ((r>>1)&3); r = lane&15 (mod 16) so (r>>1)&3 = (lane>>1)&3
    const int koff = ((lane >> 4) ^ ((lane >> 1) & 3)) * 8;
    f16x8 af[4], bf[4];
    #pragma unroll
    for (int i = 0; i < 4; i++) {
      af[i] = *(const f16x8*)&As[(wm * 64 + i * 16 + (lane & 15)) * 32 + koff];
      bf[i] = *(const f16x8*)&Bs[(wn * 64 + i * 16 + (lane & 15)) * 32 + koff];
    }
    #pragma unroll
    for (int i = 0; i < 4; i++)
      #pragma unroll
      for (int j = 0; j < 4; j++)
        acc[i][j] = __builtin_amdgcn_mfma_f32_16x16x32_f16(af[i], bf[j], acc[i][j], 0, 0, 0);
  }

  // epilogue: C/D layout col=lane&15, row=(lane>>4)*4+reg
  const int crow = (lane >> 4) * 4;
  const int ccol = lane & 15;
  #pragma unroll
  for (int j = 0; j < 4; j++) {
    const int col = n0 + wn * 64 + j * 16 + ccol;
    const float bvl = bias[col];
    #pragma unroll
    for (int i = 0; i < 4; i++) {
      #pragma unroll
      for (int r = 0; r < 4; r++) {
        const int row = m0 + wm * 64 + i * 16 + crow + r;
        const float val = acc[i][j][r] + bvl;
        if (MODE == 1) ofp[(size_t)row * DDIM + col] = val;
        else           oh[(size_t)row * DDIM + col] = (f16)val;
      }
    }
  }
}

// ------- log-sparse scores: s[bh,e,t] = q[t]·k[(t+2^e)%T] * scale -------
__global__ void score_k(const f16* __restrict__ qh, const f16* __restrict__ kh,
                        float* __restrict__ scores) {
  int bid = blockIdx.x;            // 256 blocks
  int bh = bid >> 3, tc = bid & 7;
  int b = bh >> 4, h = bh & 15;
  int t = tc * 256 + threadIdx.x;
  const f16* qrow = qh + (((size_t)(b * TSEQ + t)) << 10) + h * 64;
  float qv[64];
  #pragma unroll
  for (int c = 0; c < 8; c++) {
    f16x8 v = *(const f16x8*)(qrow + c * 8);
    #pragma unroll
    for (int j = 0; j < 8; j++) qv[c * 8 + j] = (float)v[j];
  }
  #pragma unroll
  for (int e = 0; e < 8; e++) {
    int ts = t + (1 << e);
    if (ts >= TSEQ) ts -= TSEQ;      // jnp.roll wraps
    const f16* krow = kh + (((size_t)(b * TSEQ + ts)) << 10) + h * 64;
    float s = 0.f;
    #pragma unroll
    for (int c = 0; c < 8; c++) {
      f16x8 v = *(const f16x8*)(krow + c * 8);
      #pragma unroll
      for (int j = 0; j < 8; j++) s += qv[c * 8 + j] * (float)v[j];
    }
    scores[((size_t)(bh * 8 + e) << 11) + t] = s * 0.125f;
  }
}

// ---- in-place softmax over T per (b,h,e) row: 256 rows of 2048 ----
__global__ void softmax_k(float* __restrict__ scores) {
  __shared__ float red[4];
  int row = blockIdx.x;
  float* p = scores + ((size_t)row << 11);
  int tid = threadIdx.x;
  float v[8];
  float4 a = ((const float4*)p)[tid * 2];
  float4 b = ((const float4*)p)[tid * 2 + 1];
  v[0] = a.x; v[1] = a.y; v[2] = a.z; v[3] = a.w;
  v[4] = b.x; v[5] = b.y; v[6] = b.z; v[7] = b.w;
  float m = v[0];
  #pragma unroll
  for (int j = 1; j < 8; j++) m = fmaxf(m, v[j]);
  for (int o = 32; o > 0; o >>= 1) m = fmaxf(m, __shfl_xor(m, o, 64));
  if ((tid & 63) == 0) red[tid >> 6] = m;
  __syncthreads();
  m = fmaxf(fmaxf(red[0], red[1]), fmaxf(red[2], red[3]));
  __syncthreads();
  float s = 0.f;
  #pragma unroll
  for (int j = 0; j < 8; j++) { v[j] = __expf(v[j] - m); s += v[j]; }
  for (int o = 32; o > 0; o >>= 1) s += __shfl_xor(s, o, 64);
  if ((tid & 63) == 0) red[tid >> 6] = s;
  __syncthreads();
  s = (red[0] + red[1]) + (red[2] + red[3]);
  float inv = 1.0f / s;
  float4 o1 = make_float4(v[0] * inv, v[1] * inv, v[2] * inv, v[3] * inv);
  float4 o2 = make_float4(v[4] * inv, v[5] * inv, v[6] * inv, v[7] * inv);
  ((float4*)p)[tid * 2] = o1;
  ((float4*)p)[tid * 2 + 1] = o2;
}

// ------- local windowed attention + log-sparse combine -> outh -------
__global__ __launch_bounds__(256) void attn_out_k(
    const f16* __restrict__ qh, const f16* __restrict__ kh, const f16* __restrict__ vh,
    const float* __restrict__ alpha, f16* __restrict__ outh)
{
  __shared__ f16 qL[128 * 64];     // 16 KB
  __shared__ f16 vL[271 * 64];     // 33.9 KB: rows t0-15 .. t0+255 (wrap)
  __shared__ float scL[128 * 16];  // 8 KB
  __shared__ float aL[8 * 128];    // 4 KB
  const int bh = blockIdx.x, tc = blockIdx.y;
  const int b = bh >> 4, h = bh & 15;
  const int t0 = tc * 128;
  const int tid = threadIdx.x;
  const size_t base = (((size_t)(b * TSEQ)) << 10) + h * 64;

  // phase 1: cooperative loads
  for (int idx = tid; idx < 128 * 8; idx += 256) {
    int r = idx >> 3, c = idx & 7;
    *(uint4*)&qL[r * 64 + c * 8] = *(const uint4*)(qh + base + (((size_t)(t0 + r)) << 10) + c * 8);
  }
  for (int idx = tid; idx < 271 * 8; idx += 256) {
    int j = idx >> 3, c = idx & 7;
    int r = t0 - 15 + j;
    uint4 val;
    if (r < 0) val = make_uint4(0, 0, 0, 0);
    else {
      int rr = (r >= TSEQ) ? r - TSEQ : r;     // wrap for log-sparse rows
      val = *(const uint4*)(vh + base + (((size_t)rr) << 10) + c * 8);
    }
    *(uint4*)&vL[j * 64 + c * 8] = val;
  }
  {
    int e = tid >> 5, t4 = (tid & 31) * 4;
    *(float4*)&aL[e * 128 + t4] =
        *(const float4*)(alpha + ((size_t)(bh * 8 + e) << 11) + t0 + t4);
  }
  __syncthreads();

  // phase 2: local scores (zero-pad rows give score exactly 0, kept in softmax)
  {
    const int tl = tid & 127;
    const int wg = tid >> 7;
    float qv[64];
    #pragma unroll
    for (int c = 0; c < 8; c++) {
      f16x8 v = *(const f16x8*)&qL[tl * 64 + c * 8];
      #pragma unroll
      for (int j = 0; j < 8; j++) qv[c * 8 + j] = (float)v[j];
    }
    #pragma unroll
    for (int wi = 0; wi < 8; wi++) {
      const int w = wg * 8 + wi;
      const int r = t0 + tl - 15 + w;
      float s = 0.f;
      if (r >= 0) {
        const f16* kr = kh + base + (((size_t)r) << 10);
        #pragma unroll
        for (int c = 0; c < 8; c++) {
          f16x8 v = *(const f16x8*)(kr + c * 8);
          #pragma unroll
          for (int j = 0; j < 8; j++) s += qv[c * 8 + j] * (float)v[j];
        }
      }
      scL[tl * 16 + w] = s * 0.125f;
    }
  }
  __syncthreads();

  // phase 3: 16-wide softmax per t
  if (tid < 128) {
    float sc[16];
    float m = -1e30f;
    #pragma unroll
    for (int w = 0; w < 16; w++) { sc[w] = scL[tid * 16 + w]; m = fmaxf(m, sc[w]); }
    float sum = 0.f;
    #pragma unroll
    for (int w = 0; w < 16; w++) { sc[w] = __expf(sc[w] - m); sum += sc[w]; }
    float inv = 1.0f / sum;
    #pragma unroll
    for (int w = 0; w < 16; w++) scL[tid * 16 + w] = sc[w] * inv;
  }
  __syncthreads();

  // phase 4: out = local + log-sparse
  {
    const int tl = tid >> 1;
    const int d0 = (tid & 1) * 32;
    float accv[32] = {};
    #pragma unroll
    for (int w = 0; w < 16; w++) {
      const float pw_ = scL[tl * 16 + w];
      const f16* vr = &vL[(tl + w) * 64 + d0];
      #pragma unroll
      for (int c = 0; c < 4; c++) {
        f16x8 v = *(const f16x8*)(vr + c * 8);
        #pragma unroll
        for (int j = 0; j < 8; j++) accv[c * 8 + j] += pw_ * (float)v[j];
      }
    }
    #pragma unroll
    for (int e = 0; e < 8; e++) {
      const float a = aL[e * 128 + tl];
      const f16* vr = &vL[(tl + 15 + (1 << e)) * 64 + d0];
      #pragma unroll
      for (int c = 0; c < 4; c++) {
        f16x8 v = *(const f16x8*)(vr + c * 8);
        #pragma unroll
        for (int j = 0; j < 8; j++) accv[c * 8 + j] += a * (float)v[j];
      }
    }
    f16* orow = outh + base + (((size_t)(t0 + tl)) << 10) + d0;
    #pragma unroll
    for (int c = 0; c < 4; c++) {
      f16x8 v;
      #pragma unroll
      for (int j = 0; j < 8; j++) v[j] = (f16)accv[c * 8 + j];
      *(f16x8*)(orow + c * 8) = v;
    }
  }
}

extern "C" void kernel_launch(void* const* d_in, const int* in_sizes, int n_in,
                              void* d_out, int out_size, void* d_ws, size_t ws_size,
                              hipStream_t stream) {
  (void)in_sizes; (void)n_in; (void)out_size; (void)ws_size;
  const float* x   = (const float*)d_in[0];
  const float* q_w = (const float*)d_in[1];
  const float* q_b = (const float*)d_in[2];
  const float* k_w = (const float*)d_in[3];
  const float* k_b = (const float*)d_in[4];
  const float* v_w = (const float*)d_in[5];
  const float* v_b = (const float*)d_in[6];
  const float* p_w = (const float*)d_in[7];
  const float* p_b = (const float*)d_in[8];
  float* out = (float*)d_out;

  char* ws = (char*)d_ws;
  f16* xh      = (f16*)(ws);                 //  8.4 MB
  f16* qwh     = (f16*)(ws + 8388608);       // 33.6 MB  [o][w*D+i]
  f16* kwh     = (f16*)(ws + 41943040);      // 33.6 MB
  f16* vwh     = (f16*)(ws + 75497472);      //  2.1 MB
  f16* pwh     = (f16*)(ws + 77594624);      //  2.1 MB
  f16* qh      = (f16*)(ws + 79691776);      //  8.4 MB  (B,T,D)
  f16* kh      = (f16*)(ws + 88080384);      //  8.4 MB
  f16* vh      = (f16*)(ws + 96468992);      //  8.4 MB
  f16* outh    = (f16*)(ws + 104857600);     //  8.4 MB
  float* alpha = (float*)(ws + 113246208);   //  2.1 MB  (B*H*E, T) scores->alpha
  // total 115.4 MB

  cvt_f32_f16<<<4096, 256, 0, stream>>>(x, xh, 1048576);
  cvt_f32_f16<<<1024, 256, 0, stream>>>(v_w, vwh, 262144);
  cvt_f32_f16<<<1024, 256, 0, stream>>>(p_w, pwh, 262144);
  cvt_w_transpose<<<2048, 256, 0, stream>>>(q_w, k_w, qwh, kwh);

  // fused q/k/v GEMM: yt 0-7 q (K=16384), 8-15 k, 16-23 v (K=1024)
  gemm_k<0><<<dim3(32, 24), 256, 0, stream>>>(xh, qwh, kwh, vwh, q_b, k_b, v_b,
                                              qh, kh, vh, nullptr);

  score_k<<<256, 256, 0, stream>>>(qh, kh, alpha);
  softmax_k<<<256, 256, 0, stream>>>(alpha);
  attn_out_k<<<dim3(32, 16), 256, 0, stream>>>(qh, kh, vh, alpha, outh);

  // final projection -> fp32 d_out
  gemm_k<1><<<dim3(32, 8), 256, 0, stream>>>(outh, pwh, nullptr, nullptr, p_b,
                                             nullptr, nullptr, nullptr, nullptr,
                                             nullptr, out);
}

// Round 4
// 561.315 us; speedup vs baseline: 1.3025x; 1.0690x over previous
//
#include <hip/hip_runtime.h>
#include <cstdint>
#include <cstddef>

#define TSEQ 2048
#define DDIM 1024

typedef _Float16 f16;
typedef _Float16 f16x4 __attribute__((ext_vector_type(4)));
typedef _Float16 f16x8 __attribute__((ext_vector_type(8)));
typedef float f32x4 __attribute__((ext_vector_type(4)));

// 16B of zeros for out-of-range (causal pad) staging loads
__device__ __align__(16) static const unsigned char g_zero16[16] = {};

__device__ __forceinline__ void gload_lds16(const void* g, void* l) {
  __builtin_amdgcn_global_load_lds(
      (const __attribute__((address_space(1))) void*)g,
      (__attribute__((address_space(3))) void*)l, 16, 0, 0);
}

// ---------------- fp32 -> fp16 convert (vectorized) ----------------
__global__ void cvt_f32_f16(const float* __restrict__ src, f16* __restrict__ dst, int n4) {
  int i = blockIdx.x * 256 + threadIdx.x;
  if (i >= n4) return;
  float4 v = ((const float4*)src)[i];
  f16x4 h = { (f16)v.x, (f16)v.y, (f16)v.z, (f16)v.w };
  ((f16x4*)dst)[i] = h;
}

// ------- weight convert+transpose: w[o][i][W] -> wh[o][w*D + i] -------
__global__ void cvt_w_transpose(const float* __restrict__ qw, const float* __restrict__ kw,
                                f16* __restrict__ qwh, f16* __restrict__ kwh) {
  __shared__ float tile[64 * 17];
  int o = blockIdx.x;
  const float* src;
  f16* dst;
  if (o < 1024) { src = qw + (size_t)o * 16384; dst = qwh + (size_t)o * 16384; }
  else          { src = kw + (size_t)(o - 1024) * 16384; dst = kwh + (size_t)(o - 1024) * 16384; }
  for (int i0 = 0; i0 < 1024; i0 += 64) {
    __syncthreads();
    #pragma unroll
    for (int p = 0; p < 4; p++) {
      int idx = p * 256 + threadIdx.x;           // flat = ii*16 + w
      float v = src[i0 * 16 + idx];
      tile[(idx >> 4) * 17 + (idx & 15)] = v;    // [ii][w] padded
    }
    __syncthreads();
    #pragma unroll
    for (int p = 0; p < 4; p++) {
      int idx = p * 256 + threadIdx.x;           // w = idx/64, ii = idx%64
      int w = idx >> 6, ii = idx & 63;
      dst[w * 1024 + i0 + ii] = (f16)tile[ii * 17 + w];
    }
  }
}

// ------------- fused q+k conv-GEMM, k-split, BK=64 -------------
// Block tile m=128, n=64 for BOTH q and k (A staged once, shared).
// 4 waves: wm=wid&1 (m 64-half), ks=wid>>1 (k 32-half of BK=64).
// Each wave: af[4] shared -> 16 MFMA q + 16 MFMA k per barrier.
// Rows are 128 B (8 chunks): slot = cg ^ (r&7) -> conflict-free.
// k-split partials reduced via LDS at the end (q round, then k round).
__global__ __launch_bounds__(256, 2) void gemm_qk(
    const f16* __restrict__ xh,
    const f16* __restrict__ Bq, const f16* __restrict__ Bk,
    const float* __restrict__ bq, const float* __restrict__ bk,
    f16* __restrict__ oq, f16* __restrict__ ok)
{
  __shared__ __align__(16) f16 smem[16384];   // As 8192 | Bq 4096 | Bk 4096 (f16)
  const int tid = threadIdx.x;
  const int lane = tid & 63;
  const int wid = tid >> 6;
  const int wm = wid & 1;
  const int ks = wid >> 1;

  const int m0 = blockIdx.x * 128;
  const int n0 = blockIdx.y * 64;
  const int bT = m0 & ~(TSEQ - 1);
  const int t0 = m0 & (TSEQ - 1);

  // staging lane geometry: inst covers 8 rows x 8 chunks (1 KB)
  const int srow = lane >> 3;                         // row within inst
  const int scg = ((lane & 7) ^ ((lane >> 3) & 7)) * 8; // swizzled global chunk (f16 units)

  f32x4 accq[4][4] = {};
  f32x4 acck[4][4] = {};

  // read-side slot offsets (f16 units): chunk cg = ks*4 + (lane>>4), slot = cg ^ (lane&7)
  const int slotoff = (((ks * 4 + (lane >> 4)) ^ (lane & 7)) * 8);

  for (int kk = 0; kk < 16384; kk += 64) {
    __syncthreads();
    if (wid < 2) {
      // A: 16 insts (8 per wave), rows s*8..s*8+7, tap w = kk>>10, ch i0 = kk&1023
      const int w = kk >> 10;
      const int i0 = (kk & (DDIM - 1)) + scg;
      #pragma unroll
      for (int c = 0; c < 8; c++) {
        const int s = wid * 8 + c;
        const int r = s * 8 + srow;
        const int srcT = t0 + r + w - 15;
        const void* g = (srcT >= 0)
            ? (const void*)(xh + (((size_t)(bT + srcT)) << 10) + i0)
            : (const void*)g_zero16;
        gload_lds16(g, (void*)&smem[s * 512]);
      }
    } else if (wid == 2) {
      #pragma unroll
      for (int c = 0; c < 8; c++) {
        const int r = c * 8 + srow;
        const void* g = (const void*)(Bq + ((size_t)(n0 + r) << 14) + kk + scg);
        gload_lds16(g, (void*)&smem[8192 + c * 512]);
      }
    } else {
      #pragma unroll
      for (int c = 0; c < 8; c++) {
        const int r = c * 8 + srow;
        const void* g = (const void*)(Bk + ((size_t)(n0 + r) << 14) + kk + scg);
        gload_lds16(g, (void*)&smem[12288 + c * 512]);
      }
    }
    __syncthreads();

    f16x8 af[4], bfq[4], bfk[4];
    #pragma unroll
    for (int i = 0; i < 4; i++) {
      const int r = wm * 64 + i * 16 + (lane & 15);
      af[i] = *(const f16x8*)&smem[r * 64 + slotoff];
    }
    #pragma unroll
    for (int j = 0; j < 4; j++) {
      const int r = j * 16 + (lane & 15);
      bfq[j] = *(const f16x8*)&smem[8192 + r * 64 + slotoff];
      bfk[j] = *(const f16x8*)&smem[12288 + r * 64 + slotoff];
    }
    #pragma unroll
    for (int i = 0; i < 4; i++)
      #pragma unroll
      for (int j = 0; j < 4; j++) {
        accq[i][j] = __builtin_amdgcn_mfma_f32_16x16x32_f16(af[i], bfq[j], accq[i][j], 0, 0, 0);
        acck[i][j] = __builtin_amdgcn_mfma_f32_16x16x32_f16(af[i], bfk[j], acck[i][j], 0, 0, 0);
      }
  }

  // ---- k-split reduction + epilogue. C/D: col=lane&15, row=(lane>>4)*4+reg ----
  const int crow = (lane >> 4) * 4;
  const int ccol = lane & 15;
  float* red = (float*)smem + wm * 4096;   // 64x64 f32 per m-half

  // Q round
  __syncthreads();
  if (ks == 1) {
    #pragma unroll
    for (int i = 0; i < 4; i++)
      #pragma unroll
      for (int j = 0; j < 4; j++)
        #pragma unroll
        for (int r = 0; r < 4; r++)
          red[(i * 16 + crow + r) * 64 + j * 16 + ccol] = accq[i][j][r];
  }
  __syncthreads();
  if (ks == 0) {
    #pragma unroll
    for (int j = 0; j < 4; j++) {
      const int col = n0 + j * 16 + ccol;
      const float bvl = bq[col];
      #pragma unroll
      for (int i = 0; i < 4; i++)
        #pragma unroll
        for (int r = 0; r < 4; r++) {
          const int row = m0 + wm * 64 + i * 16 + crow + r;
          const float v = accq[i][j][r] + red[(i * 16 + crow + r) * 64 + j * 16 + ccol] + bvl;
          oq[(size_t)row * DDIM + col] = (f16)v;
        }
    }
  }
  // K round
  __syncthreads();
  if (ks == 1) {
    #pragma unroll
    for (int i = 0; i < 4; i++)
      #pragma unroll
      for (int j = 0; j < 4; j++)
        #pragma unroll
        for (int r = 0; r < 4; r++)
          red[(i * 16 + crow + r) * 64 + j * 16 + ccol] = acck[i][j][r];
  }
  __syncthreads();
  if (ks == 0) {
    #pragma unroll
    for (int j = 0; j < 4; j++) {
      const int col = n0 + j * 16 + ccol;
      const float bvl = bk[col];
      #pragma unroll
      for (int i = 0; i < 4; i++)
        #pragma unroll
        for (int r = 0; r < 4; r++) {
          const int row = m0 + wm * 64 + i * 16 + crow + r;
          const float v = acck[i][j][r] + red[(i * 16 + crow + r) * 64 + j * 16 + ccol] + bvl;
          ok[(size_t)row * DDIM + col] = (f16)v;
        }
    }
  }
}

// ---------------- small GEMM (K=1024): v-proj / p-proj ----------------
// Round-3 structure: 128x128 block tile, 4 waves, BK=32, conflict-free swizzle.
// MODE 0: fp16 out (v). MODE 1: fp32 out (p).
template<int MODE>
__global__ __launch_bounds__(256, 2) void gemm_small(
    const f16* __restrict__ A, const f16* __restrict__ Bw,
    const float* __restrict__ bias, f16* __restrict__ oh, float* __restrict__ ofp)
{
  __shared__ f16 As[128 * 32];
  __shared__ f16 Bs[128 * 32];
  const int tid = threadIdx.x;
  const int lane = tid & 63;
  const int wid = tid >> 6;
  const int m0 = blockIdx.x * 128;
  const int n0 = blockIdx.y * 128;

  const int srow = lane >> 2;
  const int scg = ((lane & 3) ^ ((lane >> 3) & 3)) * 8;
  const int wm = wid & 1;
  const int wn = wid >> 1;

  f32x4 acc[4][4] = {};

  for (int kk = 0; kk < 1024; kk += 32) {
    __syncthreads();
    if (wid < 2) {
      #pragma unroll
      for (int c = 0; c < 4; c++) {
        const int r = wid * 64 + c * 16 + srow;
        const void* g = (const void*)(A + (((size_t)(m0 + r)) << 10) + kk + scg);
        gload_lds16(g, (void*)&As[(wid * 64 + c * 16) * 32]);
      }
    } else {
      #pragma unroll
      for (int c = 0; c < 4; c++) {
        const int r = (wid - 2) * 64 + c * 16 + srow;
        const void* g = (const void*)(Bw + (((size_t)(n0 + r)) << 10) + kk + scg);
        gload_lds16(g, (void*)&Bs[((wid - 2) * 64 + c * 16) * 32]);
      }
    }
    __syncthreads();
    const int koff = ((lane >> 4) ^ ((lane >> 1) & 3)) * 8;
    f16x8 af[4], bf[4];
    #pragma unroll
    for (int i = 0; i < 4; i++) {
      af[i] = *(const f16x8*)&As[(wm * 64 + i * 16 + (lane & 15)) * 32 + koff];
      bf[i] = *(const f16x8*)&Bs[(wn * 64 + i * 16 + (lane & 15)) * 32 + koff];
    }
    #pragma unroll
    for (int i = 0; i < 4; i++)
      #pragma unroll
      for (int j = 0; j < 4; j++)
        acc[i][j] = __builtin_amdgcn_mfma_f32_16x16x32_f16(af[i], bf[j], acc[i][j], 0, 0, 0);
  }

  const int crow = (lane >> 4) * 4;
  const int ccol = lane & 15;
  #pragma unroll
  for (int j = 0; j < 4; j++) {
    const int col = n0 + wn * 64 + j * 16 + ccol;
    const float bvl = bias[col];
    #pragma unroll
    for (int i = 0; i < 4; i++) {
      #pragma unroll
      for (int r = 0; r < 4; r++) {
        const int row = m0 + wm * 64 + i * 16 + crow + r;
        const float val = acc[i][j][r] + bvl;
        if (MODE == 1) ofp[(size_t)row * DDIM + col] = val;
        else           oh[(size_t)row * DDIM + col] = (f16)val;
      }
    }
  }
}

// ------- log-sparse scores: s[bh,e,t] = q[t]·k[(t+2^e)%T] * scale -------
__global__ void score_k(const f16* __restrict__ qh, const f16* __restrict__ kh,
                        float* __restrict__ scores) {
  int bid = blockIdx.x;            // 256 blocks
  int bh = bid >> 3, tc = bid & 7;
  int b = bh >> 4, h = bh & 15;
  int t = tc * 256 + threadIdx.x;
  const f16* qrow = qh + (((size_t)(b * TSEQ + t)) << 10) + h * 64;
  float qv[64];
  #pragma unroll
  for (int c = 0; c < 8; c++) {
    f16x8 v = *(const f16x8*)(qrow + c * 8);
    #pragma unroll
    for (int j = 0; j < 8; j++) qv[c * 8 + j] = (float)v[j];
  }
  #pragma unroll
  for (int e = 0; e < 8; e++) {
    int ts = t + (1 << e);
    if (ts >= TSEQ) ts -= TSEQ;      // jnp.roll wraps
    const f16* krow = kh + (((size_t)(b * TSEQ + ts)) << 10) + h * 64;
    float s = 0.f;
    #pragma unroll
    for (int c = 0; c < 8; c++) {
      f16x8 v = *(const f16x8*)(krow + c * 8);
      #pragma unroll
      for (int j = 0; j < 8; j++) s += qv[c * 8 + j] * (float)v[j];
    }
    scores[((size_t)(bh * 8 + e) << 11) + t] = s * 0.125f;
  }
}

// ---- in-place softmax over T per (b,h,e) row: 256 rows of 2048 ----
__global__ void softmax_k(float* __restrict__ scores) {
  __shared__ float red[4];
  int row = blockIdx.x;
  float* p = scores + ((size_t)row << 11);
  int tid = threadIdx.x;
  float v[8];
  float4 a = ((const float4*)p)[tid * 2];
  float4 b = ((const float4*)p)[tid * 2 + 1];
  v[0] = a.x; v[1] = a.y; v[2] = a.z; v[3] = a.w;
  v[4] = b.x; v[5] = b.y; v[6] = b.z; v[7] = b.w;
  float m = v[0];
  #pragma unroll
  for (int j = 1; j < 8; j++) m = fmaxf(m, v[j]);
  for (int o = 32; o > 0; o >>= 1) m = fmaxf(m, __shfl_xor(m, o, 64));
  if ((tid & 63) == 0) red[tid >> 6] = m;
  __syncthreads();
  m = fmaxf(fmaxf(red[0], red[1]), fmaxf(red[2], red[3]));
  __syncthreads();
  float s = 0.f;
  #pragma unroll
  for (int j = 0; j < 8; j++) { v[j] = __expf(v[j] - m); s += v[j]; }
  for (int o = 32; o > 0; o >>= 1) s += __shfl_xor(s, o, 64);
  if ((tid & 63) == 0) red[tid >> 6] = s;
  __syncthreads();
  s = (red[0] + red[1]) + (red[2] + red[3]);
  float inv = 1.0f / s;
  float4 o1 = make_float4(v[0] * inv, v[1] * inv, v[2] * inv, v[3] * inv);
  float4 o2 = make_float4(v[4] * inv, v[5] * inv, v[6] * inv, v[7] * inv);
  ((float4*)p)[tid * 2] = o1;
  ((float4*)p)[tid * 2 + 1] = o2;
}

// ------- local windowed attention + log-sparse combine -> outh -------
__global__ __launch_bounds__(256) void attn_out_k(
    const f16* __restrict__ qh, const f16* __restrict__ kh, const f16* __restrict__ vh,
    const float* __restrict__ alpha, f16* __restrict__ outh)
{
  __shared__ f16 qL[128 * 64];     // 16 KB
  __shared__ f16 vL[271 * 64];     // 33.9 KB: rows t0-15 .. t0+255 (wrap)
  __shared__ float scL[128 * 16];  // 8 KB
  __shared__ float aL[8 * 128];    // 4 KB
  const int bh = blockIdx.x, tc = blockIdx.y;
  const int b = bh >> 4, h = bh & 15;
  const int t0 = tc * 128;
  const int tid = threadIdx.x;
  const size_t base = (((size_t)(b * TSEQ)) << 10) + h * 64;

  // phase 1: cooperative loads
  for (int idx = tid; idx < 128 * 8; idx += 256) {
    int r = idx >> 3, c = idx & 7;
    *(uint4*)&qL[r * 64 + c * 8] = *(const uint4*)(qh + base + (((size_t)(t0 + r)) << 10) + c * 8);
  }
  for (int idx = tid; idx < 271 * 8; idx += 256) {
    int j = idx >> 3, c = idx & 7;
    int r = t0 - 15 + j;
    uint4 val;
    if (r < 0) val = make_uint4(0, 0, 0, 0);
    else {
      int rr = (r >= TSEQ) ? r - TSEQ : r;     // wrap for log-sparse rows
      val = *(const uint4*)(vh + base + (((size_t)rr) << 10) + c * 8);
    }
    *(uint4*)&vL[j * 64 + c * 8] = val;
  }
  {
    int e = tid >> 5, t4 = (tid & 31) * 4;
    *(float4*)&aL[e * 128 + t4] =
        *(const float4*)(alpha + ((size_t)(bh * 8 + e) << 11) + t0 + t4);
  }
  __syncthreads();

  // phase 2: local scores (zero-pad rows give score exactly 0, kept in softmax)
  {
    const int tl = tid & 127;
    const int wg = tid >> 7;
    float qv[64];
    #pragma unroll
    for (int c = 0; c < 8; c++) {
      f16x8 v = *(const f16x8*)&qL[tl * 64 + c * 8];
      #pragma unroll
      for (int j = 0; j < 8; j++) qv[c * 8 + j] = (float)v[j];
    }
    #pragma unroll
    for (int wi = 0; wi < 8; wi++) {
      const int w = wg * 8 + wi;
      const int r = t0 + tl - 15 + w;
      float s = 0.f;
      if (r >= 0) {
        const f16* kr = kh + base + (((size_t)r) << 10);
        #pragma unroll
        for (int c = 0; c < 8; c++) {
          f16x8 v = *(const f16x8*)(kr + c * 8);
          #pragma unroll
          for (int j = 0; j < 8; j++) s += qv[c * 8 + j] * (float)v[j];
        }
      }
      scL[tl * 16 + w] = s * 0.125f;
    }
  }
  __syncthreads();

  // phase 3: 16-wide softmax per t
  if (tid < 128) {
    float sc[16];
    float m = -1e30f;
    #pragma unroll
    for (int w = 0; w < 16; w++) { sc[w] = scL[tid * 16 + w]; m = fmaxf(m, sc[w]); }
    float sum = 0.f;
    #pragma unroll
    for (int w = 0; w < 16; w++) { sc[w] = __expf(sc[w] - m); sum += sc[w]; }
    float inv = 1.0f / sum;
    #pragma unroll
    for (int w = 0; w < 16; w++) scL[tid * 16 + w] = sc[w] * inv;
  }
  __syncthreads();

  // phase 4: out = local + log-sparse
  {
    const int tl = tid >> 1;
    const int d0 = (tid & 1) * 32;
    float accv[32] = {};
    #pragma unroll
    for (int w = 0; w < 16; w++) {
      const float pw_ = scL[tl * 16 + w];
      const f16* vr = &vL[(tl + w) * 64 + d0];
      #pragma unroll
      for (int c = 0; c < 4; c++) {
        f16x8 v = *(const f16x8*)(vr + c * 8);
        #pragma unroll
        for (int j = 0; j < 8; j++) accv[c * 8 + j] += pw_ * (float)v[j];
      }
    }
    #pragma unroll
    for (int e = 0; e < 8; e++) {
      const float a = aL[e * 128 + tl];
      const f16* vr = &vL[(tl + 15 + (1 << e)) * 64 + d0];
      #pragma unroll
      for (int c = 0; c < 4; c++) {
        f16x8 v = *(const f16x8*)(vr + c * 8);
        #pragma unroll
        for (int j = 0; j < 8; j++) accv[c * 8 + j] += a * (float)v[j];
      }
    }
    f16* orow = outh + base + (((size_t)(t0 + tl)) << 10) + d0;
    #pragma unroll
    for (int c = 0; c < 4; c++) {
      f16x8 v;
      #pragma unroll
      for (int j = 0; j < 8; j++) v[j] = (f16)accv[c * 8 + j];
      *(f16x8*)(orow + c * 8) = v;
    }
  }
}

extern "C" void kernel_launch(void* const* d_in, const int* in_sizes, int n_in,
                              void* d_out, int out_size, void* d_ws, size_t ws_size,
                              hipStream_t stream) {
  (void)in_sizes; (void)n_in; (void)out_size; (void)ws_size;
  const float* x   = (const float*)d_in[0];
  const float* q_w = (const float*)d_in[1];
  const float* q_b = (const float*)d_in[2];
  const float* k_w = (const float*)d_in[3];
  const float* k_b = (const float*)d_in[4];
  const float* v_w = (const float*)d_in[5];
  const float* v_b = (const float*)d_in[6];
  const float* p_w = (const float*)d_in[7];
  const float* p_b = (const float*)d_in[8];
  float* out = (float*)d_out;

  char* ws = (char*)d_ws;
  f16* xh      = (f16*)(ws);                 //  8.4 MB
  f16* qwh     = (f16*)(ws + 8388608);       // 33.6 MB  [o][w*D+i]
  f16* kwh     = (f16*)(ws + 41943040);      // 33.6 MB
  f16* vwh     = (f16*)(ws + 75497472);      //  2.1 MB
  f16* pwh     = (f16*)(ws + 77594624);      //  2.1 MB
  f16* qh      = (f16*)(ws + 79691776);      //  8.4 MB  (B,T,D)
  f16* kh      = (f16*)(ws + 88080384);      //  8.4 MB
  f16* vh      = (f16*)(ws + 96468992);      //  8.4 MB
  f16* outh    = (f16*)(ws + 104857600);     //  8.4 MB
  float* alpha = (float*)(ws + 113246208);   //  2.1 MB  (B*H*E, T) scores->alpha
  // total 115.4 MB

  cvt_f32_f16<<<4096, 256, 0, stream>>>(x, xh, 1048576);
  cvt_f32_f16<<<1024, 256, 0, stream>>>(v_w, vwh, 262144);
  cvt_f32_f16<<<1024, 256, 0, stream>>>(p_w, pwh, 262144);
  cvt_w_transpose<<<2048, 256, 0, stream>>>(q_w, k_w, qwh, kwh);

  // fused q+k conv-GEMM (A shared), 512 blocks = 2/CU
  gemm_qk<<<dim3(32, 16), 256, 0, stream>>>(xh, qwh, kwh, q_b, k_b, qh, kh);
  // v projection
  gemm_small<0><<<dim3(32, 8), 256, 0, stream>>>(xh, vwh, v_b, vh, nullptr);

  score_k<<<256, 256, 0, stream>>>(qh, kh, alpha);
  softmax_k<<<256, 256, 0, stream>>>(alpha);
  attn_out_k<<<dim3(32, 16), 256, 0, stream>>>(qh, kh, vh, alpha, outh);

  // final projection -> fp32 d_out
  gemm_small<1><<<dim3(32, 8), 256, 0, stream>>>(outh, pwh, p_b, nullptr, out);
}

// Round 5
// 546.148 us; speedup vs baseline: 1.3387x; 1.0278x over previous
//
#include <hip/hip_runtime.h>
#include <cstdint>
#include <cstddef>

#define TSEQ 2048
#define DDIM 1024

typedef _Float16 f16;
typedef _Float16 f16x2 __attribute__((ext_vector_type(2)));
typedef _Float16 f16x4 __attribute__((ext_vector_type(4)));
typedef _Float16 f16x8 __attribute__((ext_vector_type(8)));
typedef float f32x4 __attribute__((ext_vector_type(4)));

// q,k,v live in (b,h,t,d) layout: ((b*16+h)*2048 + t)*64 + d  -> per-head rows
// are contiguous 128B, so attention-side reads coalesce. x and outh stay (b,t,d).

// 16B of zeros for out-of-range (causal pad) staging loads
__device__ __align__(16) static const unsigned char g_zero16[16] = {};

__device__ __forceinline__ void gload_lds16(const void* g, void* l) {
  __builtin_amdgcn_global_load_lds(
      (const __attribute__((address_space(1))) void*)g,
      (__attribute__((address_space(3))) void*)l, 16, 0, 0);
}

// ---------------- fp32 -> fp16 convert (vectorized) ----------------
__global__ void cvt_f32_f16(const float* __restrict__ src, f16* __restrict__ dst, int n4) {
  int i = blockIdx.x * 256 + threadIdx.x;
  if (i >= n4) return;
  float4 v = ((const float4*)src)[i];
  f16x4 h = { (f16)v.x, (f16)v.y, (f16)v.z, (f16)v.w };
  ((f16x4*)dst)[i] = h;
}

// ------- weight convert+transpose: w[o][i][W] -> wh[o][w*D + i] -------
__global__ void cvt_w_transpose(const float* __restrict__ qw, const float* __restrict__ kw,
                                f16* __restrict__ qwh, f16* __restrict__ kwh) {
  __shared__ float tile[64 * 17];
  int o = blockIdx.x;
  const float* src;
  f16* dst;
  if (o < 1024) { src = qw + (size_t)o * 16384; dst = qwh + (size_t)o * 16384; }
  else          { src = kw + (size_t)(o - 1024) * 16384; dst = kwh + (size_t)(o - 1024) * 16384; }
  for (int i0 = 0; i0 < 1024; i0 += 64) {
    __syncthreads();
    #pragma unroll
    for (int p = 0; p < 4; p++) {
      int idx = p * 256 + threadIdx.x;           // flat = ii*16 + w
      float v = src[i0 * 16 + idx];
      tile[(idx >> 4) * 17 + (idx & 15)] = v;    // [ii][w] padded
    }
    __syncthreads();
    #pragma unroll
    for (int p = 0; p < 4; p++) {
      int idx = p * 256 + threadIdx.x;           // w = idx/64, ii = idx%64
      int w = idx >> 6, ii = idx & 63;
      dst[w * 1024 + i0 + ii] = (f16)tile[ii * 17 + w];
    }
  }
}

// ------------- fused q+k conv-GEMM, k-split, BK=64, double-buffered -------------
// Block tile m=128, n=64 for BOTH q and k (A staged once, shared).
// 4 waves: wm=wid&1 (m 64-half), ks=wid>>1 (k 32-half of BK=64).
// DOUBLE BUFFER: stage(kk+64) issued right after the barrier -> the barrier's
// forced vmcnt(0) only drains loads that had a full compute phase in flight.
// Rows are 128 B (8 chunks): slot = cg ^ (r&7) -> conflict-free.
__global__ __launch_bounds__(256, 2) void gemm_qk(
    const f16* __restrict__ xh,
    const f16* __restrict__ Bq, const f16* __restrict__ Bk,
    const float* __restrict__ bq, const float* __restrict__ bk,
    f16* __restrict__ oq, f16* __restrict__ ok)
{
  __shared__ __align__(16) f16 smem[32768];   // 2 stages x (As 8192 | Bq 4096 | Bk 4096)
  const int tid = threadIdx.x;
  const int lane = tid & 63;
  const int wid = tid >> 6;
  const int wm = wid & 1;
  const int ks = wid >> 1;

  const int m0 = blockIdx.x * 128;
  const int n0 = blockIdx.y * 64;
  const int bT = m0 & ~(TSEQ - 1);
  const int t0 = m0 & (TSEQ - 1);

  const int srow = lane >> 3;                           // staging row within inst
  const int scg = ((lane & 7) ^ ((lane >> 3) & 7)) * 8; // swizzled global chunk (f16 units)

  f32x4 accq[4][4] = {};
  f32x4 acck[4][4] = {};

  // read-side slot offsets: chunk cg = ks*4 + (lane>>4), slot = cg ^ (lane&7)
  const int slotoff = (((ks * 4 + (lane >> 4)) ^ (lane & 7)) * 8);

  auto stage = [&](int kk, int buf) {
    f16* sb = &smem[buf * 16384];
    if (wid < 2) {
      const int w = kk >> 10;
      const int i0 = (kk & (DDIM - 1)) + scg;
      #pragma unroll
      for (int c = 0; c < 8; c++) {
        const int s = wid * 8 + c;
        const int r = s * 8 + srow;
        const int srcT = t0 + r + w - 15;
        const void* g = (srcT >= 0)
            ? (const void*)(xh + (((size_t)(bT + srcT)) << 10) + i0)
            : (const void*)g_zero16;
        gload_lds16(g, (void*)&sb[s * 512]);
      }
    } else if (wid == 2) {
      #pragma unroll
      for (int c = 0; c < 8; c++) {
        const int r = c * 8 + srow;
        const void* g = (const void*)(Bq + ((size_t)(n0 + r) << 14) + kk + scg);
        gload_lds16(g, (void*)&sb[8192 + c * 512]);
      }
    } else {
      #pragma unroll
      for (int c = 0; c < 8; c++) {
        const int r = c * 8 + srow;
        const void* g = (const void*)(Bk + ((size_t)(n0 + r) << 14) + kk + scg);
        gload_lds16(g, (void*)&sb[12288 + c * 512]);
      }
    }
  };

  stage(0, 0);
  for (int kk = 0; kk < 16384; kk += 64) {
    const int buf = (kk >> 6) & 1;
    __syncthreads();
    if (kk + 64 < 16384) stage(kk + 64, buf ^ 1);

    const f16* sb = &smem[buf * 16384];
    f16x8 af[4], bfq[4], bfk[4];
    #pragma unroll
    for (int i = 0; i < 4; i++) {
      const int r = wm * 64 + i * 16 + (lane & 15);
      af[i] = *(const f16x8*)&sb[r * 64 + slotoff];
    }
    #pragma unroll
    for (int j = 0; j < 4; j++) {
      const int r = j * 16 + (lane & 15);
      bfq[j] = *(const f16x8*)&sb[8192 + r * 64 + slotoff];
      bfk[j] = *(const f16x8*)&sb[12288 + r * 64 + slotoff];
    }
    #pragma unroll
    for (int i = 0; i < 4; i++)
      #pragma unroll
      for (int j = 0; j < 4; j++) {
        accq[i][j] = __builtin_amdgcn_mfma_f32_16x16x32_f16(af[i], bfq[j], accq[i][j], 0, 0, 0);
        acck[i][j] = __builtin_amdgcn_mfma_f32_16x16x32_f16(af[i], bfk[j], acck[i][j], 0, 0, 0);
      }
  }

  // ---- k-split reduction + epilogue. C/D: col=lane&15, row=(lane>>4)*4+reg ----
  // out layout (b,h,t,d): h = n0>>6 (constant per block), d = col&63
  const int crow = (lane >> 4) * 4;
  const int ccol = lane & 15;
  const int hh = n0 >> 6;
  float* red = (float*)smem + wm * 4096;   // 64x64 f32 per m-half

  // Q round
  __syncthreads();
  if (ks == 1) {
    #pragma unroll
    for (int i = 0; i < 4; i++)
      #pragma unroll
      for (int j = 0; j < 4; j++)
        #pragma unroll
        for (int r = 0; r < 4; r++)
          red[(i * 16 + crow + r) * 64 + j * 16 + ccol] = accq[i][j][r];
  }
  __syncthreads();
  if (ks == 0) {
    #pragma unroll
    for (int j = 0; j < 4; j++) {
      const int col = n0 + j * 16 + ccol;
      const float bvl = bq[col];
      const int d = j * 16 + ccol;
      #pragma unroll
      for (int i = 0; i < 4; i++)
        #pragma unroll
        for (int r = 0; r < 4; r++) {
          const int row = m0 + wm * 64 + i * 16 + crow + r;
          const int b = row >> 11, t = row & (TSEQ - 1);
          const float v = accq[i][j][r] + red[(i * 16 + crow + r) * 64 + j * 16 + ccol] + bvl;
          oq[((size_t)(b * 16 + hh) * TSEQ + t) * 64 + d] = (f16)v;
        }
    }
  }
  // K round
  __syncthreads();
  if (ks == 1) {
    #pragma unroll
    for (int i = 0; i < 4; i++)
      #pragma unroll
      for (int j = 0; j < 4; j++)
        #pragma unroll
        for (int r = 0; r < 4; r++)
          red[(i * 16 + crow + r) * 64 + j * 16 + ccol] = acck[i][j][r];
  }
  __syncthreads();
  if (ks == 0) {
    #pragma unroll
    for (int j = 0; j < 4; j++) {
      const int col = n0 + j * 16 + ccol;
      const float bvl = bk[col];
      const int d = j * 16 + ccol;
      #pragma unroll
      for (int i = 0; i < 4; i++)
        #pragma unroll
        for (int r = 0; r < 4; r++) {
          const int row = m0 + wm * 64 + i * 16 + crow + r;
          const int b = row >> 11, t = row & (TSEQ - 1);
          const float v = acck[i][j][r] + red[(i * 16 + crow + r) * 64 + j * 16 + ccol] + bvl;
          ok[((size_t)(b * 16 + hh) * TSEQ + t) * 64 + d] = (f16)v;
        }
    }
  }
}

// ---------------- small GEMM (K=1024): v-proj / p-proj ----------------
// MODE 0: fp16 out to (b,h,t,d) layout (v). MODE 1: fp32 out to (b,t,d) d_out (p).
template<int MODE>
__global__ __launch_bounds__(256, 2) void gemm_small(
    const f16* __restrict__ A, const f16* __restrict__ Bw,
    const float* __restrict__ bias, f16* __restrict__ oh, float* __restrict__ ofp)
{
  __shared__ f16 As[128 * 32];
  __shared__ f16 Bs[128 * 32];
  const int tid = threadIdx.x;
  const int lane = tid & 63;
  const int wid = tid >> 6;
  const int m0 = blockIdx.x * 128;
  const int n0 = blockIdx.y * 128;

  const int srow = lane >> 2;
  const int scg = ((lane & 3) ^ ((lane >> 3) & 3)) * 8;
  const int wm = wid & 1;
  const int wn = wid >> 1;

  f32x4 acc[4][4] = {};

  for (int kk = 0; kk < 1024; kk += 32) {
    __syncthreads();
    if (wid < 2) {
      #pragma unroll
      for (int c = 0; c < 4; c++) {
        const int r = wid * 64 + c * 16 + srow;
        const void* g = (const void*)(A + (((size_t)(m0 + r)) << 10) + kk + scg);
        gload_lds16(g, (void*)&As[(wid * 64 + c * 16) * 32]);
      }
    } else {
      #pragma unroll
      for (int c = 0; c < 4; c++) {
        const int r = (wid - 2) * 64 + c * 16 + srow;
        const void* g = (const void*)(Bw + (((size_t)(n0 + r)) << 10) + kk + scg);
        gload_lds16(g, (void*)&Bs[((wid - 2) * 64 + c * 16) * 32]);
      }
    }
    __syncthreads();
    const int koff = ((lane >> 4) ^ ((lane >> 1) & 3)) * 8;
    f16x8 af[4], bf[4];
    #pragma unroll
    for (int i = 0; i < 4; i++) {
      af[i] = *(const f16x8*)&As[(wm * 64 + i * 16 + (lane & 15)) * 32 + koff];
      bf[i] = *(const f16x8*)&Bs[(wn * 64 + i * 16 + (lane & 15)) * 32 + koff];
    }
    #pragma unroll
    for (int i = 0; i < 4; i++)
      #pragma unroll
      for (int j = 0; j < 4; j++)
        acc[i][j] = __builtin_amdgcn_mfma_f32_16x16x32_f16(af[i], bf[j], acc[i][j], 0, 0, 0);
  }

  const int crow = (lane >> 4) * 4;
  const int ccol = lane & 15;
  #pragma unroll
  for (int j = 0; j < 4; j++) {
    const int col = n0 + wn * 64 + j * 16 + ccol;
    const float bvl = bias[col];
    #pragma unroll
    for (int i = 0; i < 4; i++) {
      #pragma unroll
      for (int r = 0; r < 4; r++) {
        const int row = m0 + wm * 64 + i * 16 + crow + r;
        const float val = acc[i][j][r] + bvl;
        if (MODE == 1) {
          ofp[(size_t)row * DDIM + col] = val;
        } else {
          const int b = row >> 11, t = row & (TSEQ - 1);
          const int h = col >> 6, d = col & 63;
          oh[((size_t)(b * 16 + h) * TSEQ + t) * 64 + d] = (f16)val;
        }
      }
    }
  }
}

// ------- log-sparse scores, (b,h,t,d) layout, coalesced + fdot2 -------
__global__ __launch_bounds__(256) void score_k(const f16* __restrict__ qh,
                                               const f16* __restrict__ kh,
                                               float* __restrict__ scores) {
  const int bid = blockIdx.x;
  const int bh = bid >> 3, tc = bid & 7;
  const int tid = threadIdx.x;
  const int wave = tid >> 6, lane = tid & 63;
  const int tr = lane >> 3, dc = lane & 7;
  const size_t base = ((size_t)bh) << 17;   // bh*2048*64
  const f16* qb = qh + base;
  const f16* kb = kh + base;

  #pragma unroll
  for (int p = 0; p < 8; p++) {
    const int t = tc * 256 + wave * 64 + p * 8 + tr;
    f16x8 qv = *(const f16x8*)(qb + (size_t)t * 64 + dc * 8);
    const f16x2* qp = (const f16x2*)&qv;
    #pragma unroll
    for (int e = 0; e < 8; e++) {
      const int ts = (t + (1 << e)) & (TSEQ - 1);
      f16x8 kv = *(const f16x8*)(kb + (size_t)ts * 64 + dc * 8);
      const f16x2* kp = (const f16x2*)&kv;
      float s = 0.f;
      #pragma unroll
      for (int j = 0; j < 4; j++) s = __builtin_amdgcn_fdot2(qp[j], kp[j], s, false);
      s += __shfl_xor(s, 1, 64);
      s += __shfl_xor(s, 2, 64);
      s += __shfl_xor(s, 4, 64);
      if (dc == 0) scores[((size_t)(bh * 8 + e) << 11) + t] = s * 0.125f;
    }
  }
}

// ---- in-place softmax over T per (b,h,e) row: 256 rows of 2048 ----
__global__ void softmax_k(float* __restrict__ scores) {
  __shared__ float red[4];
  int row = blockIdx.x;
  float* p = scores + ((size_t)row << 11);
  int tid = threadIdx.x;
  float v[8];
  float4 a = ((const float4*)p)[tid * 2];
  float4 b = ((const float4*)p)[tid * 2 + 1];
  v[0] = a.x; v[1] = a.y; v[2] = a.z; v[3] = a.w;
  v[4] = b.x; v[5] = b.y; v[6] = b.z; v[7] = b.w;
  float m = v[0];
  #pragma unroll
  for (int j = 1; j < 8; j++) m = fmaxf(m, v[j]);
  for (int o = 32; o > 0; o >>= 1) m = fmaxf(m, __shfl_xor(m, o, 64));
  if ((tid & 63) == 0) red[tid >> 6] = m;
  __syncthreads();
  m = fmaxf(fmaxf(red[0], red[1]), fmaxf(red[2], red[3]));
  __syncthreads();
  float s = 0.f;
  #pragma unroll
  for (int j = 0; j < 8; j++) { v[j] = __expf(v[j] - m); s += v[j]; }
  for (int o = 32; o > 0; o >>= 1) s += __shfl_xor(s, o, 64);
  if ((tid & 63) == 0) red[tid >> 6] = s;
  __syncthreads();
  s = (red[0] + red[1]) + (red[2] + red[3]);
  float inv = 1.0f / s;
  float4 o1 = make_float4(v[0] * inv, v[1] * inv, v[2] * inv, v[3] * inv);
  float4 o2 = make_float4(v[4] * inv, v[5] * inv, v[6] * inv, v[7] * inv);
  ((float4*)p)[tid * 2] = o1;
  ((float4*)p)[tid * 2 + 1] = o2;
}

// ------- local windowed attention + log-sparse combine -> outh (b,t,d) -------
__global__ __launch_bounds__(256) void attn_out_k(
    const f16* __restrict__ qh, const f16* __restrict__ kh, const f16* __restrict__ vh,
    const float* __restrict__ alpha, f16* __restrict__ outh)
{
  __shared__ f16 qL[64 * 64];      //  8 KB rows t0..t0+63
  __shared__ f16 kL[80 * 64];      // 10 KB rows t0-15..t0+63 (79 used)
  __shared__ f16 vL[208 * 64];     // 26 KB rows t0-15..t0+191 (207 used, wrap)
  __shared__ float scL[64 * 16];   //  4 KB
  __shared__ float aL[8 * 64];     //  2 KB
  const int bh = blockIdx.x, tc = blockIdx.y;
  const int t0 = tc * 64;
  const int tid = threadIdx.x;
  const size_t base = ((size_t)bh) << 17;

  // phase 1: cooperative coalesced loads (chunk-swizzled: slot = c ^ (r&7))
  for (int idx = tid; idx < 64 * 8; idx += 256) {
    int r = idx >> 3, c = idx & 7, sl = c ^ (r & 7);
    *(uint4*)&qL[r * 64 + sl * 8] = *(const uint4*)(qh + base + (size_t)(t0 + r) * 64 + c * 8);
  }
  for (int idx = tid; idx < 79 * 8; idx += 256) {
    int r = idx >> 3, c = idx & 7, sl = c ^ (r & 7);
    int g = t0 - 15 + r;
    uint4 val = (g < 0) ? make_uint4(0, 0, 0, 0)
                        : *(const uint4*)(kh + base + (size_t)g * 64 + c * 8);
    *(uint4*)&kL[r * 64 + sl * 8] = val;
  }
  for (int idx = tid; idx < 207 * 8; idx += 256) {
    int r = idx >> 3, c = idx & 7, sl = c ^ (r & 7);
    int g = t0 - 15 + r;
    uint4 val;
    if (g < 0) val = make_uint4(0, 0, 0, 0);
    else {
      if (g >= TSEQ) g -= TSEQ;
      val = *(const uint4*)(vh + base + (size_t)g * 64 + c * 8);
    }
    *(uint4*)&vL[r * 64 + sl * 8] = val;
  }
  for (int idx = tid; idx < 512; idx += 256) {
    int e = idx >> 6, i = idx & 63;
    aL[e * 64 + i] = alpha[((size_t)(bh * 8 + e) << 11) + t0 + i];
  }
  __syncthreads();

  // phase 2: local scores via fdot2 (zero-filled pad rows give exact 0)
  {
    const int tl = tid & 63;
    const int wg = tid >> 6;
    f16x8 qv[8];
    #pragma unroll
    for (int c = 0; c < 8; c++) qv[c] = *(const f16x8*)&qL[tl * 64 + ((c ^ (tl & 7)) * 8)];
    const f16x2* qp = (const f16x2*)&qv[0];
    #pragma unroll
    for (int wi = 0; wi < 4; wi++) {
      const int w = wg * 4 + wi;
      const int r = tl + w;               // kL row index (kL[0] = t0-15)
      float s = 0.f;
      #pragma unroll
      for (int c = 0; c < 8; c++) {
        f16x8 kv = *(const f16x8*)&kL[r * 64 + ((c ^ (r & 7)) * 8)];
        const f16x2* kp = (const f16x2*)&kv;
        #pragma unroll
        for (int j = 0; j < 4; j++) s = __builtin_amdgcn_fdot2(qp[c * 4 + j], kp[j], s, false);
      }
      scL[tl * 16 + w] = s * 0.125f;
    }
  }
  __syncthreads();

  // phase 3: 16-wide softmax per t
  if (tid < 64) {
    float sc[16];
    float m = -1e30f;
    #pragma unroll
    for (int w = 0; w < 16; w++) { sc[w] = scL[tid * 16 + w]; m = fmaxf(m, sc[w]); }
    float sum = 0.f;
    #pragma unroll
    for (int w = 0; w < 16; w++) { sc[w] = __expf(sc[w] - m); sum += sc[w]; }
    float inv = 1.0f / sum;
    #pragma unroll
    for (int w = 0; w < 16; w++) scL[tid * 16 + w] = sc[w] * inv;
  }
  __syncthreads();

  // phase 4: out = local + log-sparse; 4 threads per row, 16 dims each
  {
    const int tl = tid >> 2;
    const int qd = tid & 3;              // d-quarter
    float accv[16] = {};
    #pragma unroll
    for (int w = 0; w < 16; w++) {
      const float pw_ = scL[tl * 16 + w];
      const int r = tl + w;
      #pragma unroll
      for (int c2 = 0; c2 < 2; c2++) {
        const int c = qd * 2 + c2;
        f16x8 v = *(const f16x8*)&vL[r * 64 + ((c ^ (r & 7)) * 8)];
        #pragma unroll
        for (int j = 0; j < 8; j++) accv[c2 * 8 + j] += pw_ * (float)v[j];
      }
    }
    #pragma unroll
    for (int e = 0; e < 8; e++) {
      const float a = aL[e * 64 + tl];
      const int r = tl + 15 + (1 << e);
      #pragma unroll
      for (int c2 = 0; c2 < 2; c2++) {
        const int c = qd * 2 + c2;
        f16x8 v = *(const f16x8*)&vL[r * 64 + ((c ^ (r & 7)) * 8)];
        #pragma unroll
        for (int j = 0; j < 8; j++) accv[c2 * 8 + j] += a * (float)v[j];
      }
    }
    const int b = bh >> 4, h = bh & 15;
    f16* orow = outh + ((size_t)(b * TSEQ + t0 + tl)) * DDIM + h * 64 + qd * 16;
    #pragma unroll
    for (int c2 = 0; c2 < 2; c2++) {
      f16x8 v;
      #pragma unroll
      for (int j = 0; j < 8; j++) v[j] = (f16)accv[c2 * 8 + j];
      *(f16x8*)(orow + c2 * 8) = v;
    }
  }
}

extern "C" void kernel_launch(void* const* d_in, const int* in_sizes, int n_in,
                              void* d_out, int out_size, void* d_ws, size_t ws_size,
                              hipStream_t stream) {
  (void)in_sizes; (void)n_in; (void)out_size; (void)ws_size;
  const float* x   = (const float*)d_in[0];
  const float* q_w = (const float*)d_in[1];
  const float* q_b = (const float*)d_in[2];
  const float* k_w = (const float*)d_in[3];
  const float* k_b = (const float*)d_in[4];
  const float* v_w = (const float*)d_in[5];
  const float* v_b = (const float*)d_in[6];
  const float* p_w = (const float*)d_in[7];
  const float* p_b = (const float*)d_in[8];
  float* out = (float*)d_out;

  char* ws = (char*)d_ws;
  f16* xh      = (f16*)(ws);                 //  8.4 MB (b,t,d)
  f16* qwh     = (f16*)(ws + 8388608);       // 33.6 MB  [o][w*D+i]
  f16* kwh     = (f16*)(ws + 41943040);      // 33.6 MB
  f16* vwh     = (f16*)(ws + 75497472);      //  2.1 MB
  f16* pwh     = (f16*)(ws + 77594624);      //  2.1 MB
  f16* qh      = (f16*)(ws + 79691776);      //  8.4 MB (b,h,t,d)
  f16* kh      = (f16*)(ws + 88080384);      //  8.4 MB (b,h,t,d)
  f16* vh      = (f16*)(ws + 96468992);      //  8.4 MB (b,h,t,d)
  f16* outh    = (f16*)(ws + 104857600);     //  8.4 MB (b,t,d)
  float* alpha = (float*)(ws + 113246208);   //  2.1 MB  (B*H*E, T)
  // total 115.4 MB

  cvt_f32_f16<<<4096, 256, 0, stream>>>(x, xh, 1048576);
  cvt_f32_f16<<<1024, 256, 0, stream>>>(v_w, vwh, 262144);
  cvt_f32_f16<<<1024, 256, 0, stream>>>(p_w, pwh, 262144);
  cvt_w_transpose<<<2048, 256, 0, stream>>>(q_w, k_w, qwh, kwh);

  // fused q+k conv-GEMM (A shared, double-buffered), 512 blocks = 2/CU
  gemm_qk<<<dim3(32, 16), 256, 0, stream>>>(xh, qwh, kwh, q_b, k_b, qh, kh);
  // v projection
  gemm_small<0><<<dim3(32, 8), 256, 0, stream>>>(xh, vwh, v_b, vh, nullptr);

  score_k<<<256, 256, 0, stream>>>(qh, kh, alpha);
  softmax_k<<<256, 256, 0, stream>>>(alpha);
  attn_out_k<<<dim3(32, 32), 256, 0, stream>>>(qh, kh, vh, alpha, outh);

  // final projection -> fp32 d_out
  gemm_small<1><<<dim3(32, 8), 256, 0, stream>>>(outh, pwh, p_b, nullptr, out);
}